// Round 8
// baseline (90.521 us; speedup 1.0000x reference)
//
#include <hip/hip_runtime.h>
#include <math.h>

#define EPS2f 0.25f
#define EPS4f 0.0625f

// ---------------------------------------------------------------------------
// Kernel 1: precompute per-(ij,k) tables (unchanged from round 6, which passed).
//   AB4 (float4 view)[k2*1024 + ij] = { A(2k2), B2(2k2), A(2k2+1), B2(2k2+1) }
//   KVP4(float4 view)[(ij>>1)*64+k] = { K(ij_e), Vm(ij_e), K(ij_o), Vm(ij_o) }
//   C0 [ij] = sum_k ( mu_t^2/Sigma + log(Sigma) )
// ---------------------------------------------------------------------------
__global__ __launch_bounds__(256) void precomp_kernel(
    const float* __restrict__ Mu0, const float* __restrict__ Mu1,
    const float* __restrict__ S0,  const float* __restrict__ S1,
    const float* __restrict__ tptr,
    float2* __restrict__ AB2, float2* __restrict__ KV2,
    float* __restrict__ C0)
{
    const int tid = threadIdx.x;
    const int k   = tid & 63;
    const int ij  = (blockIdx.x << 2) + (tid >> 6);
    const int i   = ij >> 5;              // N0=32
    const int j   = ij & 31;              // N1=32
    const float t   = *tptr;
    const float omt = 1.0f - t;

    const float s0 = S0[i * 64 + k];
    const float s1 = S1[j * 64 + k];
    const float m0 = Mu0[i * 64 + k];
    const float m1 = Mu1[j * 64 + k];

    const float ds  = sqrtf(4.0f * s0 * s1 + EPS4f);
    const float cs  = 0.5f * (ds - EPS2f);
    const float mt  = omt * m0 + t * m1;
    const float sig = omt * omt * s0 + t * t * s1
                    + 2.0f * t * omt * (cs + 0.5f * EPS2f);
    const float isig = 1.0f / sig;
    const float st = t * s1 - omt * s0 + (omt - t) * cs - EPS2f * t;
    const float kk = st * isig;
    const float v  = m1 - m0;

    AB2[((k >> 1) << 11) + (ij << 1) + (k & 1)] = make_float2(isig, 2.0f * mt * isig);
    KV2[((ij >> 1) << 7) + (k << 1) + (ij & 1)] = make_float2(kk, v - kk * mt);

    float c = mt * mt * isig + __logf(sig);
    #pragma unroll
    for (int off = 32; off >= 1; off >>= 1)
        c += __shfl_xor(c, off, 64);
    if (k == 0) C0[ij] = c;
}

// ---------------------------------------------------------------------------
// Kernel 2: main. Block = (ij-eighth e x 32 batch rows). Grid 256 = 8 x 32.
// 1024 threads = 16 waves. Table traffic: 128 KB/block x 256 = 32 MB.
// Phase A: thread = (rg = tid>>7 -> rows 4rg..4rg+3, ij_l = tid&127).
// Phase B: wave w: g = w>>1, half = w&1 — exactly the tile the same wave
//          produced in phase A -> no barrier. Partials straight to global.
// ---------------------------------------------------------------------------
__global__ __launch_bounds__(1024, 4) void gmm_main_kernel(
    const float* __restrict__ X,   const float* __restrict__ Lam,
    const float* __restrict__ C0,
    const float4* __restrict__ AB4, const float4* __restrict__ KVP4,
    float* __restrict__ num_p, float* __restrict__ den_p)
{
    __shared__ float Xs[64 * 36];     // [k][row], rows padded to 36 (16B align)
    __shared__ float Wl[32 * 128];    // [row][ij_l]

    const int tid   = threadIdx.x;
    const int lane  = tid & 63;
    const int w     = tid >> 6;           // 0..15
    const int e     = blockIdx.x & 7;     // ij-eighth
    const int chunk = blockIdx.x >> 3;    // 32-row chunk

    // ---- Stage X rows [chunk*32, +32) as Xs[k][row] ----
    {
        int t0 = tid;
        int row = t0 >> 6, k = t0 & 63;
        Xs[k * 36 + row] = X[(chunk * 32 + row) * 64 + k];   // coalesced
        t0 = tid + 1024;
        row = t0 >> 6; k = t0 & 63;
        Xs[k * 36 + row] = X[(chunk * 32 + row) * 64 + k];
    }
    __syncthreads();

    // ---- Phase A ----
    const int rg   = tid >> 7;            // row-group: rows 4rg..4rg+3
    const int ij_l = tid & 127;
    const int ij_g = (e << 7) + ij_l;
    float q0 = 0.f, q1 = 0.f, q2 = 0.f, q3 = 0.f;
    #pragma unroll 8
    for (int k2 = 0; k2 < 32; ++k2) {
        const float4 ab = AB4[(k2 << 10) + ij_g];   // coalesced 16B/lane
        const float4 x0 = *(const float4*)&Xs[(2 * k2) * 36 + 4 * rg];     // bcast
        const float4 x1 = *(const float4*)&Xs[(2 * k2 + 1) * 36 + 4 * rg]; // bcast
        q0 = fmaf(fmaf(ab.x, x0.x, -ab.y), x0.x, q0);
        q1 = fmaf(fmaf(ab.x, x0.y, -ab.y), x0.y, q1);
        q2 = fmaf(fmaf(ab.x, x0.z, -ab.y), x0.z, q2);
        q3 = fmaf(fmaf(ab.x, x0.w, -ab.y), x0.w, q3);
        q0 = fmaf(fmaf(ab.z, x1.x, -ab.w), x1.x, q0);
        q1 = fmaf(fmaf(ab.z, x1.y, -ab.w), x1.y, q1);
        q2 = fmaf(fmaf(ab.z, x1.z, -ab.w), x1.z, q2);
        q3 = fmaf(fmaf(ab.z, x1.w, -ab.w), x1.w, q3);
    }
    const float c0 = C0[ij_g];
    const float lm = Lam[ij_g];
    #define WCALC(q) (__expf(fminf(fmaxf(-0.5f * ((q) + c0), -50.f), 50.f)) * lm)
    Wl[(4 * rg + 0) * 128 + ij_l] = WCALC(q0);   // lanes consecutive: no conflict
    Wl[(4 * rg + 1) * 128 + ij_l] = WCALC(q1);
    Wl[(4 * rg + 2) * 128 + ij_l] = WCALC(q2);
    Wl[(4 * rg + 3) * 128 + ij_l] = WCALC(q3);
    #undef WCALC

    // ---- Phase B (same wave tile as phase A: no barrier) ----
    const int g    = w >> 1;              // rows 4g..4g+3  (== rg of this wave)
    const int half = w & 1;               // ij half
    const float x0v = Xs[lane * 36 + 4 * g + 0];
    const float x1v = Xs[lane * 36 + 4 * g + 1];
    const float x2v = Xs[lane * 36 + 4 * g + 2];
    const float x3v = Xs[lane * 36 + 4 * g + 3];
    float n0 = 0.f, n1 = 0.f, n2 = 0.f, n3 = 0.f;
    float d0 = 0.f, d1 = 0.f, d2 = 0.f, d3 = 0.f;
    const int pbase = (e << 6) + (half << 5);   // global ij-pair base

    #pragma unroll 8
    for (int p = 0; p < 32; ++p) {
        const float4 kv = KVP4[((pbase + p) << 6) + lane]; // {K_e,V_e,K_o,V_o}
        const int ijp = (half << 6) + 2 * p;               // even local ij
        const float2 wr0 = *(const float2*)&Wl[(4 * g + 0) * 128 + ijp]; // bcast
        const float2 wr1 = *(const float2*)&Wl[(4 * g + 1) * 128 + ijp];
        const float2 wr2 = *(const float2*)&Wl[(4 * g + 2) * 128 + ijp];
        const float2 wr3 = *(const float2*)&Wl[(4 * g + 3) * 128 + ijp];
        float u;
        u = fmaf(kv.x, x0v, kv.y); n0 = fmaf(wr0.x, u, n0);
        u = fmaf(kv.z, x0v, kv.w); n0 = fmaf(wr0.y, u, n0);
        d0 += wr0.x + wr0.y;
        u = fmaf(kv.x, x1v, kv.y); n1 = fmaf(wr1.x, u, n1);
        u = fmaf(kv.z, x1v, kv.w); n1 = fmaf(wr1.y, u, n1);
        d1 += wr1.x + wr1.y;
        u = fmaf(kv.x, x2v, kv.y); n2 = fmaf(wr2.x, u, n2);
        u = fmaf(kv.z, x2v, kv.w); n2 = fmaf(wr2.y, u, n2);
        d2 += wr2.x + wr2.y;
        u = fmaf(kv.x, x3v, kv.y); n3 = fmaf(wr3.x, u, n3);
        u = fmaf(kv.z, x3v, kv.w); n3 = fmaf(wr3.y, u, n3);
        d3 += wr3.x + wr3.y;
    }

    // ---- Write per-wave partials (coalesced 256 B stores) ----
    const int pid = ((e * 32 + chunk) * 16 + w);
    num_p[(pid * 4 + 0) * 64 + lane] = n0;
    num_p[(pid * 4 + 1) * 64 + lane] = n1;
    num_p[(pid * 4 + 2) * 64 + lane] = n2;
    num_p[(pid * 4 + 3) * 64 + lane] = n3;
    if (lane == 0) {   // d accumulated from broadcasts: identical on all lanes
        den_p[pid * 4 + 0] = d0;
        den_p[pid * 4 + 1] = d1;
        den_p[pid * 4 + 2] = d2;
        den_p[pid * 4 + 3] = d3;
    }
}

// ---------------------------------------------------------------------------
// Kernel 3: sum 16 partials (8 eighths x 2 halves) per (row,k), divide, store.
// ---------------------------------------------------------------------------
__global__ __launch_bounds__(256) void finalize_kernel(
    const float* __restrict__ num_p, const float* __restrict__ den_p,
    float* __restrict__ out)
{
    const int idx   = blockIdx.x * 256 + threadIdx.x;  // [0, 65536)
    const int k     = idx & 63;
    const int b     = idx >> 6;        // batch row [0, 1024)
    const int chunk = b >> 5;
    const int row   = b & 31;
    const int g     = row >> 2, s = row & 3;
    float sum = 0.f, den = 0.f;
    #pragma unroll
    for (int e = 0; e < 8; ++e) {
        #pragma unroll
        for (int half = 0; half < 2; ++half) {
            const int pid = ((e * 32 + chunk) * 16 + (g * 2 + half));
            sum += num_p[(pid * 4 + s) * 64 + k];   // coalesced per (e,half)
            den += den_p[pid * 4 + s];
        }
    }
    out[idx] = sum / den;
}

extern "C" void kernel_launch(void* const* d_in, const int* in_sizes, int n_in,
                              void* d_out, int out_size, void* d_ws, size_t ws_size,
                              hipStream_t stream) {
    const float* X   = (const float*)d_in[0];
    const float* Mu0 = (const float*)d_in[1];
    const float* Mu1 = (const float*)d_in[2];
    const float* S0  = (const float*)d_in[3];
    const float* S1  = (const float*)d_in[4];
    const float* Lam = (const float*)d_in[5];
    const float* t   = (const float*)d_in[6];
    float* out = (float*)d_out;

    // Compact workspace layout: high-water mark 5.5 MiB + 64 KiB (R7 reached
    // 10 MiB and aborted; keeping everything low in case ws is smaller than
    // the poison-fill suggested).
    char* ws = (char*)d_ws;
    float2* AB2  = (float2*)(ws);                        // 512 KiB
    float2* KV2  = (float2*)(ws + (512 << 10));          // 512 KiB
    float*  C0   = (float*)(ws + (1024 << 10));          // 4 KiB
    float*  nump = (float*)(ws + 1310720u);              // +1.25 MiB, 4 MiB
    float*  denp = (float*)(ws + 5767168u);              // +5.5 MiB, 64 KiB

    precomp_kernel<<<256, 256, 0, stream>>>(Mu0, Mu1, S0, S1, t, AB2, KV2, C0);
    gmm_main_kernel<<<256, 1024, 0, stream>>>(X, Lam, C0,
                                              (const float4*)AB2,
                                              (const float4*)KV2, nump, denp);
    finalize_kernel<<<256, 256, 0, stream>>>(nump, denp, out);
}